// Round 8
// baseline (112.888 us; speedup 1.0000x reference)
//
#include <hip/hip_runtime.h>
#include <math.h>

constexpr int NBINS = 1025;              // 2048/2 + 1
constexpr int NROWS = 128 * 192;         // B * P
constexpr int RPB   = 16;                // rows per block (4 per wave)
constexpr int NBLK  = NROWS / RPB;       // 1536 blocks

// Round-to-nearest-even float -> bf16 (finite inputs only).
__device__ inline unsigned int f2bf(float f) {
    unsigned int u = __float_as_uint(f);
    return (u + 0x7FFFu + ((u >> 16) & 1u)) >> 16;
}

// Output layout (empirical, R3/R4): one uint32 per bin, LOW half = im
// (flat elem 2k), HIGH half = re (flat elem 2k+1), bf16 RNE.
//
// H(theta) = (d + i*g1*s)/(d + i*g2*s), theta = pi*k/1024, h = theta/2.
// Product form (cancellation-safe near resonance):
//   dp = (sh - st)(sh + st), sh = sin(w0/2), st = sin(h); d = 2*dp
//   s  = sin(theta)
//   re = (dp^2 + (a^2/4) s^2) / (dp^2 + (g2^2/4) s^2)
//   im = ((g1-g2)/2)*s*dp     / (dp^2 + (g2^2/4) s^2)
//
// R8: no LDS, no barriers, no libm in the hot path. v_sin_f32 takes
// REVOLUTIONS (ISA S3), and all angles are exact pow2 fractions:
//   st = v_sin(k/4096), s = v_sin(k/2048), sh/ch = v_sin/v_cos(c/88200).
// Stores: dwordx2 parity trick (row base 8B-aligned at k = row&1); the
// one uncovered bin per row (k=1024 even rows / k=0 odd rows) is exactly
// H=1 (num==den at theta=0,pi) -> constant 0x3F800000.
__global__ __launch_bounds__(256) void eq_kernel(
    const float* __restrict__ center,
    const float* __restrict__ gain,
    const float* __restrict__ q,
    unsigned int* __restrict__ out)
{
    const int tid  = threadIdx.x;
    const int wave = tid >> 6;
    const int lane = tid & 63;
    const int rbase = blockIdx.x * RPB + wave * 4;

    for (int j = 0; j < 4; ++j) {
        const int row = rbase + j;
        // Wave-uniform row params -> scalar loads + broadcast trans ops.
        float rev = 1.1337868480725623e-5f * center[row];  // (w0/2)/(2pi) = c/88200
        float sh  = __builtin_amdgcn_sinf(rev);            // sin(w0/2)
        float ch  = __builtin_amdgcn_cosf(rev);            // cos(w0/2)
        float A   = exp2f(0.08304820237218406f * gain[row]); // 10^(gain/40)
        float alpha = sh * ch / q[row];                    // sin(w0)/(2q)
        float g2 = alpha / A;
        float A2 = 0.25f * alpha * alpha;                  // (g1*g2)/4
        float G2 = 0.25f * g2 * g2;
        float GD = 0.5f * (alpha * A - g2);                // (g1-g2)/2

        const int koff = row & 1;
        unsigned int* __restrict__ orow = out + (size_t)row * NBINS;
        uint2* __restrict__ op = (uint2*)(orow + koff);    // 8B-aligned by parity
        if (lane == 0)
            orow[koff ? 0 : 1024] = 0x3F800000u;           // H = 1 exactly
        #pragma unroll
        for (int i = 0; i < 8; ++i) {
            const int k = koff + 2 * lane + (i << 7);
            float k0 = (float)k, k1 = (float)(k + 1);
            float st0 = __builtin_amdgcn_sinf(k0 * 2.44140625e-4f);  // sin(h),     k/4096
            float s0  = __builtin_amdgcn_sinf(k0 * 4.8828125e-4f);   // sin(theta), k/2048
            float st1 = __builtin_amdgcn_sinf(k1 * 2.44140625e-4f);
            float s1  = __builtin_amdgcn_sinf(k1 * 4.8828125e-4f);
            float dp0 = (sh - st0) * (sh + st0);
            float dp1 = (sh - st1) * (sh + st1);
            float D20 = dp0 * dp0,  D21 = dp1 * dp1;
            float S20 = s0 * s0,    S21 = s1 * s1;
            float i0 = __builtin_amdgcn_rcpf(fmaf(G2, S20, D20));
            float i1 = __builtin_amdgcn_rcpf(fmaf(G2, S21, D21));
            float re0 = fmaf(A2, S20, D20) * i0;
            float re1 = fmaf(A2, S21, D21) * i1;
            float im0 = GD * s0 * dp0 * i0;
            float im1 = GD * s1 * dp1 * i1;
            op[lane + (i << 6)] = make_uint2(f2bf(im0) | (f2bf(re0) << 16),
                                             f2bf(im1) | (f2bf(re1) << 16));
        }
    }
}

extern "C" void kernel_launch(void* const* d_in, const int* in_sizes, int n_in,
                              void* d_out, int out_size, void* d_ws, size_t ws_size,
                              hipStream_t stream) {
    const float* center = (const float*)d_in[0];
    const float* gain   = (const float*)d_in[1];
    const float* q      = (const float*)d_in[2];
    eq_kernel<<<NBLK, 256, 0, stream>>>(center, gain, q, (unsigned int*)d_out);
}